// Round 3
// baseline (134.584 us; speedup 1.0000x reference)
//
#include <hip/hip_runtime.h>
#include <hip/hip_bf16.h>
#include <stdint.h>

// Problem constants
#define B_N   8192
#define H_K   1024
#define O_N   256
#define E_N   16
#define RCAP  1024                 // per-expert row capacity (counts ~512 +- 63; >8 sigma)

// GEMM tiling
#define TILE_M    64
#define TILE_N    128
#define BK        64
#define NITER     (H_K / BK)       // 16
#define MAX_TILES (RCAP / TILE_M)  // 16

// ws byte offsets
#define WS_CURSOR   0
#define WS_ROWBUF   1024                        // 16*1024*4   = 64 KB
#define WS_XSORT    131072                      // 16*1024*1024*2 = 32 MB (bf16, expert-sorted)
#define WS_WBF16    (WS_XSORT + 33554432 + 131072)  // 16*256*1024*2 = 8 MB (bf16 W)

typedef __attribute__((ext_vector_type(8))) short  short8;   // 8 x bf16 (4 VGPRs)
typedef __attribute__((ext_vector_type(4))) float  float4v;  // MFMA C/D frag / 16B load

__device__ __forceinline__ short f32_to_bf16(float f) {
    uint32_t u = __builtin_bit_cast(uint32_t, f);
    u += 0x7fffu + ((u >> 16) & 1u);          // round-to-nearest-even
    return (short)(u >> 16);
}

__device__ __forceinline__ short8 cvt8(float4v v0, float4v v1) {
    short8 s;
    s[0] = f32_to_bf16(v0[0]); s[1] = f32_to_bf16(v0[1]);
    s[2] = f32_to_bf16(v0[2]); s[3] = f32_to_bf16(v0[3]);
    s[4] = f32_to_bf16(v1[0]); s[5] = f32_to_bf16(v1[1]);
    s[6] = f32_to_bf16(v1[2]); s[7] = f32_to_bf16(v1[3]);
    return s;
}

__device__ __forceinline__ float4v mfma16(short8 a, short8 b, float4v c) {
    return __builtin_amdgcn_mfma_f32_16x16x32_bf16(a, b, c, 0, 0, 0);
}

// async global -> LDS, 16 bytes/lane (dest = wave-uniform base + lane*16)
__device__ __forceinline__ void gl2lds16(const void* gsrc, void* ldst) {
    __builtin_amdgcn_global_load_lds(
        (const __attribute__((address_space(1))) uint32_t*)gsrc,
        (__attribute__((address_space(3))) uint32_t*)ldst, 16, 0, 0);
}

// ---------------------------------------------------------------- K1: bucket (blocks 0..31) + W->bf16 (all blocks)
__global__ __launch_bounds__(256) void
k_prep(const float* __restrict__ W, const int* __restrict__ num, const int* __restrict__ c,
       int* __restrict__ cursor, int* __restrict__ rowbuf, short* __restrict__ Wb) {
    const int tid = threadIdx.x;
    const int bx  = blockIdx.x;

    if (bx < 32) {                              // bucket 256 rows per block
        __shared__ int lcnt[E_N], lbase[E_N], lcnt2[E_N];
        if (tid < E_N) { lcnt[tid] = 0; lcnt2[tid] = 0; }
        __syncthreads();
        const int i = bx * 256 + tid;
        const int e = c[num[i]];
        atomicAdd(&lcnt[e], 1);
        __syncthreads();
        if (tid < E_N) lbase[tid] = atomicAdd(&cursor[tid], lcnt[tid]);
        __syncthreads();
        const int r = atomicAdd(&lcnt2[e], 1);
        const int p = lbase[e] + r;
        if (p < RCAP) rowbuf[e * RCAP + p] = i;
    }

    // W fp32 -> bf16, grid-stride over 8-element chunks
    const int nchunk = E_N * O_N * H_K / 8;     // 524288
    const int stride = gridDim.x * blockDim.x;  // 65536
    for (int ch = bx * 256 + tid; ch < nchunk; ch += stride) {
        const float4v* src = (const float4v*)(W + (size_t)ch * 8);
        *(short8*)(Wb + (size_t)ch * 8) = cvt8(src[0], src[1]);
    }
}

// ---------------------------------------------------------------- K2: gather x rows into expert-sorted bf16
// grid (E_N, RCAP/32); block handles 32 rows x 1024 cols. Zero-fills to 64-row tile boundary.
__global__ __launch_bounds__(256) void
k_reorder(const float* __restrict__ x, const int* __restrict__ cursor,
          const int* __restrict__ rowbuf, short* __restrict__ xsrt) {
    const int e = blockIdx.x, t = blockIdx.y, tid = threadIdx.x;
    int count = cursor[e]; if (count > RCAP) count = RCAP;
    const int lim = (count + TILE_M - 1) & ~(TILE_M - 1);
    const int p0 = t * 32;
    if (p0 >= lim) return;

#pragma unroll
    for (int it = 0; it < 16; ++it) {           // 32 rows x 128 chunks of 8 elems
        const int idx = tid + it * 256;
        const int rl = idx >> 7, ch = idx & 127;
        const int p = p0 + rl;
        if (p >= lim) continue;
        short8 s;
        if (p < count) {
            const int grow = rowbuf[e * RCAP + p];
            const float4v* src = (const float4v*)(x + (size_t)grow * H_K + ch * 8);
            s = cvt8(src[0], src[1]);
        } else {
            s = (short8)(short)0;
        }
        *(short8*)(xsrt + ((size_t)(e * RCAP + p)) * H_K + ch * 8) = s;
    }
}

// ---------------------------------------------------------------- K3: grouped bf16 GEMM + bias + sigmoid
// grid (e, mtile, ntile). All-bf16 operands, global_load_lds staging, XOR-swizzled LDS,
// double-buffered, 1 barrier/iter.
__global__ __launch_bounds__(256) void
k_gemm(const short* __restrict__ xs_g, const short* __restrict__ Wb,
       const float* __restrict__ bias, const int* __restrict__ cursor,
       const int* __restrict__ rowbuf, float* __restrict__ out) {
    const int e = blockIdx.x;
    int count = cursor[e]; if (count > RCAP) count = RCAP;
    const int m0 = blockIdx.y * TILE_M;
    if (m0 >= count) return;
    const int n0 = blockIdx.z * TILE_N;

    __shared__ short xs[2][TILE_M][BK];         // 2 x 8 KB, unpadded (global_load_lds)
    __shared__ short wsh[2][TILE_N][BK];        // 2 x 16 KB
    __shared__ int   rows[TILE_M];

    const int tid = threadIdx.x;
    if (tid < TILE_M)
        rows[tid] = (m0 + tid < count) ? rowbuf[e * RCAP + m0 + tid] : -1;

    const int lane = tid & 63;
    const int wave = tid >> 6;
    const int wm = wave >> 1, wn = wave & 1;
    const int quad = lane >> 4, l16 = lane & 15;

    // staging lane map: instr writes 8 rows x 8 chunks; lane i -> row sub=i/8, phys chunk i%8
    // XOR swizzle: phys chunk (i%8) holds logical chunk (i%8)^sub
    const int sub = lane >> 3;
    const int clx = (lane & 7) ^ sub;           // logical k-chunk this lane fetches

    const short* xseg = xs_g + (size_t)(e * RCAP + m0) * H_K;
    const short* wseg = Wb + (size_t)(e * O_N + n0) * H_K;

    auto issue = [&](int buf, int k0) {
#pragma unroll
        for (int u = 0; u < 2; ++u) {           // x tile: 8 instrs of 8 rows, 2 per wave
            const int q = wave * 2 + u;
            gl2lds16(xseg + (size_t)(q * 8 + sub) * H_K + k0 + clx * 8, &xs[buf][q * 8][0]);
        }
#pragma unroll
        for (int u = 0; u < 4; ++u) {           // W tile: 16 instrs of 8 rows, 4 per wave
            const int q = wave * 4 + u;
            gl2lds16(wseg + (size_t)(q * 8 + sub) * H_K + k0 + clx * 8, &wsh[buf][q * 8][0]);
        }
    };

    float4v acc[2][4];
#pragma unroll
    for (int i = 0; i < 2; ++i)
#pragma unroll
        for (int j = 0; j < 4; ++j) acc[i][j] = (float4v)0.0f;

    issue(0, 0);

    for (int k = 0; k < NITER; ++k) {
        const int cur = k & 1;
        __syncthreads();                        // drains loads into buf[cur]
        if (k + 1 < NITER) issue(1 - cur, (k + 1) * BK);  // in flight across MFMA phase

#pragma unroll
        for (int ks = 0; ks < 2; ++ks) {
            const int cl = ks * 4 + quad;       // logical k-chunk for this MFMA
            const int cp = (cl ^ (l16 & 7)) * 8; // swizzled phys offset (shorts)
            short8 a0 = *(const short8*)&xs[cur][wm * 32 + l16][cp];
            short8 a1 = *(const short8*)&xs[cur][wm * 32 + 16 + l16][cp];
            short8 b0 = *(const short8*)&wsh[cur][wn * 64 + l16][cp];
            short8 b1 = *(const short8*)&wsh[cur][wn * 64 + 16 + l16][cp];
            short8 b2 = *(const short8*)&wsh[cur][wn * 64 + 32 + l16][cp];
            short8 b3 = *(const short8*)&wsh[cur][wn * 64 + 48 + l16][cp];
            acc[0][0] = mfma16(a0, b0, acc[0][0]);
            acc[0][1] = mfma16(a0, b1, acc[0][1]);
            acc[0][2] = mfma16(a0, b2, acc[0][2]);
            acc[0][3] = mfma16(a0, b3, acc[0][3]);
            acc[1][0] = mfma16(a1, b0, acc[1][0]);
            acc[1][1] = mfma16(a1, b1, acc[1][1]);
            acc[1][2] = mfma16(a1, b2, acc[1][2]);
            acc[1][3] = mfma16(a1, b3, acc[1][3]);
        }
    }

    // ---- epilogue: bias + sigmoid + scatter-store (C/D: col=lane&15, row=quad*4+reg)
#pragma unroll
    for (int jn = 0; jn < 4; ++jn) {
        const int colg = n0 + wn * 64 + jn * 16 + l16;
        const float bv = bias[e * O_N + colg];
#pragma unroll
        for (int jm = 0; jm < 2; ++jm) {
            const int rl = wm * 32 + jm * 16 + quad * 4;
#pragma unroll
            for (int reg = 0; reg < 4; ++reg) {
                const int rid = rows[rl + reg];
                if (rid >= 0) {
                    const float v = acc[jm][jn][reg] + bv;
                    out[(size_t)rid * O_N + colg] = 1.0f / (1.0f + __expf(-v));
                }
            }
        }
    }
}

// ----------------------------------------------------------------
extern "C" void kernel_launch(void* const* d_in, const int* in_sizes, int n_in,
                              void* d_out, int out_size, void* d_ws, size_t ws_size,
                              hipStream_t stream) {
    const float* x   = (const float*)d_in[0];   // [B, H]
    const float* W   = (const float*)d_in[1];   // [E, O, H]
    const float* b   = (const float*)d_in[2];   // [E, O]
    const int*   num = (const int*)d_in[3];     // [B]
    const int*   c   = (const int*)d_in[4];     // [CMAP]
    float* out = (float*)d_out;                 // [B, O]

    char*  ws     = (char*)d_ws;
    int*   cursor = (int*)(ws + WS_CURSOR);
    int*   rowbuf = (int*)(ws + WS_ROWBUF);
    short* xsrt   = (short*)(ws + WS_XSORT);
    short* Wb     = (short*)(ws + WS_WBF16);

    hipMemsetAsync(cursor, 0, E_N * sizeof(int), stream);
    k_prep<<<256, 256, 0, stream>>>(W, num, c, cursor, rowbuf, Wb);

    dim3 gr(E_N, RCAP / 32);
    k_reorder<<<gr, 256, 0, stream>>>(x, cursor, rowbuf, xsrt);

    dim3 gg(E_N, MAX_TILES, O_N / TILE_N);
    k_gemm<<<gg, 256, 0, stream>>>(xsrt, Wb, b, cursor, rowbuf, out);
}

// Round 4
// 115.947 us; speedup vs baseline: 1.1607x; 1.1607x over previous
//
#include <hip/hip_runtime.h>
#include <hip/hip_bf16.h>
#include <stdint.h>

// Problem constants
#define B_N   8192
#define H_K   1024
#define O_N   256
#define E_N   16
#define RCAP  1024                 // per-expert capacity (counts ~512 +- 63)

// GEMM tiling
#define TILE_M    32
#define TILE_N    128
#define BK        64
#define NITER     (H_K / BK)       // 16
#define MTILES    (RCAP / TILE_M)  // 32
#define LDS_LD    (BK + 8)         // x tile pad: 72 shorts = 144B stride

// ws byte offsets
#define WS_CURSOR   0
#define WS_ROWBUF   1024                   // 16*1024*4 = 64 KB
#define WS_WBF16    131072                 // 16*256*1024*2 = 8 MB bf16 W

typedef __attribute__((ext_vector_type(8))) short  short8;   // 8 x bf16
typedef __attribute__((ext_vector_type(4))) float  float4v;

__device__ __forceinline__ short f32_to_bf16(float f) {
    uint32_t u = __builtin_bit_cast(uint32_t, f);
    u += 0x7fffu + ((u >> 16) & 1u);       // round-to-nearest-even
    return (short)(u >> 16);
}

__device__ __forceinline__ short8 cvt8(float4v v0, float4v v1) {
    short8 s;
    s[0] = f32_to_bf16(v0[0]); s[1] = f32_to_bf16(v0[1]);
    s[2] = f32_to_bf16(v0[2]); s[3] = f32_to_bf16(v0[3]);
    s[4] = f32_to_bf16(v1[0]); s[5] = f32_to_bf16(v1[1]);
    s[6] = f32_to_bf16(v1[2]); s[7] = f32_to_bf16(v1[3]);
    return s;
}

__device__ __forceinline__ float4v mfma16(short8 a, short8 b, float4v c) {
    return __builtin_amdgcn_mfma_f32_16x16x32_bf16(a, b, c, 0, 0, 0);
}

// async global -> LDS, 16 B/lane (LDS dest = wave-uniform base + lane*16)
__device__ __forceinline__ void gl2lds16(const void* gsrc, void* ldst) {
    __builtin_amdgcn_global_load_lds(
        (const __attribute__((address_space(1))) uint32_t*)gsrc,
        (__attribute__((address_space(3))) uint32_t*)ldst, 16, 0, 0);
}

// ---------------------------------------------------------------- K1: bucket (blocks 0..15, atomic-free) + W->bf16 (all)
__global__ __launch_bounds__(256) void
k_prep(const float* __restrict__ W, const int* __restrict__ num, const int* __restrict__ c,
       int* __restrict__ cursor, int* __restrict__ rowbuf, short* __restrict__ Wb) {
    const int tid = threadIdx.x;
    const int bx  = blockIdx.x;

    if (bx < E_N) {
        // block bx collects rows whose expert == bx. No atomics, no cursor init.
        unsigned mask = 0;
#pragma unroll
        for (int u = 0; u < 32; ++u) {
            const int i = u * 256 + tid;           // coalesced num reads
            const int e = c[num[i]];
            mask |= (unsigned)(e == bx) << u;
        }
        const int cnt = __popc(mask);
        // two-level exclusive scan: shfl within wave, wave sums in LDS
        const int lane = tid & 63, wv = tid >> 6;
        int incl = cnt;
#pragma unroll
        for (int d = 1; d < 64; d <<= 1) {
            int v = __shfl_up(incl, d, 64);
            if (lane >= d) incl += v;
        }
        __shared__ int wsum[4];
        if (lane == 63) wsum[wv] = incl;
        __syncthreads();
        int base = 0;
        for (int w = 0; w < wv; ++w) base += wsum[w];
        int pos = base + incl - cnt;               // exclusive prefix
        for (int u = 0; u < 32; ++u)
            if ((mask >> u) & 1u) rowbuf[bx * RCAP + pos++] = u * 256 + tid;
        if (tid == 255) cursor[bx] = base + incl;  // total count
    }

    // W fp32 -> bf16, grid-stride over 8-elem chunks (all 256 blocks)
    const int nchunk = E_N * O_N * H_K / 8;        // 524288
    const int stride = 256 * 256;
    for (int ch = bx * 256 + tid; ch < nchunk; ch += stride) {
        const float4v* src = (const float4v*)(W + (size_t)ch * 8);
        *(short8*)(Wb + (size_t)ch * 8) = cvt8(src[0], src[1]);
    }
}

// ---------------------------------------------------------------- K2: grouped GEMM + bias + sigmoid
// grid (e, mtile, ntile): linear%8 == e%8 -> expert pinned to one XCD (W[e] L2-resident).
// x: gathered fp32 -> cvt -> padded LDS (register-prefetched).
// W: bf16 via global_load_lds (XOR-swizzled, unpadded), double-buffered, 1 barrier/iter.
__global__ __launch_bounds__(256) void
k_gemm(const float* __restrict__ x, const short* __restrict__ Wb,
       const float* __restrict__ bias, const int* __restrict__ cursor,
       const int* __restrict__ rowbuf, float* __restrict__ out) {
    const int e = blockIdx.x;
    int count = cursor[e]; if (count > RCAP) count = RCAP;
    const int m0 = blockIdx.y * TILE_M;
    if (m0 >= count) return;
    const int n0 = blockIdx.z * TILE_N;

    __shared__ short xs[2][TILE_M][LDS_LD];    // 2 x 4.6 KB, padded (ds_write path)
    __shared__ short wsh[2][TILE_N][BK];       // 2 x 16 KB, unpadded (global_load_lds)
    __shared__ int   rows[TILE_M];

    const int tid = threadIdx.x;
    if (tid < TILE_M)
        rows[tid] = (m0 + tid < count) ? rowbuf[e * RCAP + m0 + tid] : -1;
    __syncthreads();

    const int r8   = tid >> 3;                 // x-stage row 0..31
    const int scol = (tid & 7) * 8;            // 8 fp32 per thread
    const int xrow = rows[r8];

    const int lane = tid & 63;
    const int wave = tid >> 6;
    const int wm = wave >> 1, wn = wave & 1;
    const int quad = lane >> 4, l16 = lane & 15;

    // W staging lane map: 8 rows x 8 chunks per instr; lane -> row sub, phys chunk lane&7
    // XOR swizzle: phys chunk holds logical chunk (lane&7)^sub
    const int sub = lane >> 3;
    const int clx = (lane & 7) ^ sub;

    const short* wseg = Wb + (size_t)(e * O_N + n0) * H_K;

    float4v xv0, xv1;                          // x register prefetch
    auto load_x = [&](int k0) {
        if (xrow >= 0) {
            const float4v* p = (const float4v*)(x + (size_t)xrow * H_K + k0 + scol);
            xv0 = p[0]; xv1 = p[1];
        } else { xv0 = (float4v)0.0f; xv1 = (float4v)0.0f; }
    };
    auto store_x = [&](int buf) {
        *(short8*)&xs[buf][r8][scol] = cvt8(xv0, xv1);
    };
    auto issue_w = [&](int buf, int k0) {
#pragma unroll
        for (int u = 0; u < 4; ++u) {          // 16 instrs of 8 rows, 4 per wave
            const int q = wave * 4 + u;
            gl2lds16(wseg + (size_t)(q * 8 + sub) * H_K + k0 + clx * 8,
                     &wsh[buf][q * 8][0]);
        }
    };

    float4v acc[4];
#pragma unroll
    for (int j = 0; j < 4; ++j) acc[j] = (float4v)0.0f;

    // prologue
    load_x(0);
    issue_w(0, 0);
    store_x(0);

    for (int k = 0; k < NITER; ++k) {
        const int cur = k & 1;
        __syncthreads();                       // drains W loads + x writes into buf[cur]
        if (k + 1 < NITER) {
            load_x((k + 1) * BK);
            issue_w(1 - cur, (k + 1) * BK);    // in flight across MFMA phase
        }

#pragma unroll
        for (int ks = 0; ks < 2; ++ks) {
            const int kx = ks * 32 + quad * 8;             // x: logical (padded, no swizzle)
            const int cw = (((ks * 4 + quad) ^ (l16 & 7))) * 8;  // W: swizzled phys offset
            short8 a  = *(const short8*)&xs[cur][wm * 16 + l16][kx];
            short8 b0 = *(const short8*)&wsh[cur][wn * 64 + l16][cw];
            short8 b1 = *(const short8*)&wsh[cur][wn * 64 + 16 + l16][cw];
            short8 b2 = *(const short8*)&wsh[cur][wn * 64 + 32 + l16][cw];
            short8 b3 = *(const short8*)&wsh[cur][wn * 64 + 48 + l16][cw];
            acc[0] = mfma16(a, b0, acc[0]);
            acc[1] = mfma16(a, b1, acc[1]);
            acc[2] = mfma16(a, b2, acc[2]);
            acc[3] = mfma16(a, b3, acc[3]);
        }

        if (k + 1 < NITER) store_x(1 - cur);   // x vmcnt wait lands here, post-MFMA
    }

    // epilogue: bias + sigmoid + scatter-store (C/D: col=lane&15, row=quad*4+reg)
#pragma unroll
    for (int j = 0; j < 4; ++j) {
        const int colg = n0 + wn * 64 + j * 16 + l16;
        const float bv = bias[e * O_N + colg];
        const int rl = wm * 16 + quad * 4;
#pragma unroll
        for (int reg = 0; reg < 4; ++reg) {
            const int rid = rows[rl + reg];
            if (rid >= 0) {
                const float v = acc[j][reg] + bv;
                out[(size_t)rid * O_N + colg] = 1.0f / (1.0f + __expf(-v));
            }
        }
    }
}

// ----------------------------------------------------------------
extern "C" void kernel_launch(void* const* d_in, const int* in_sizes, int n_in,
                              void* d_out, int out_size, void* d_ws, size_t ws_size,
                              hipStream_t stream) {
    const float* x   = (const float*)d_in[0];   // [B, H]
    const float* W   = (const float*)d_in[1];   // [E, O, H]
    const float* b   = (const float*)d_in[2];   // [E, O]
    const int*   num = (const int*)d_in[3];     // [B]
    const int*   c   = (const int*)d_in[4];     // [CMAP]
    float* out = (float*)d_out;                 // [B, O]

    char*  ws     = (char*)d_ws;
    int*   cursor = (int*)(ws + WS_CURSOR);
    int*   rowbuf = (int*)(ws + WS_ROWBUF);
    short* Wb     = (short*)(ws + WS_WBF16);

    k_prep<<<256, 256, 0, stream>>>(W, num, c, cursor, rowbuf, Wb);

    dim3 gg(E_N, MTILES, O_N / TILE_N);
    k_gemm<<<gg, 256, 0, stream>>>(x, Wb, b, cursor, rowbuf, out);
}